// Round 5
// baseline (188.083 us; speedup 1.0000x reference)
//
#include <hip/hip_runtime.h>
#include <cstdint>

// Self-attention (q=k=v=x), B=4, S=4096, D=64, fp32 in/out.
// Round 5: register-diet so 512x512 fits 2 blocks/CU (16 waves/CU).
// __launch_bounds__(512,4): 4 waves/EU -> k = 4*4/8 = 2 blocks/CU, reg cap
// 512/4 = 128 total (VGPR+AGPR unified on gfx950). Diet: single QK acc
// (chained MFMA, C-forwarding is free), no K prefetch, PV split by d-half,
// readfirstlane'd uniform address bases, native __bf16 casts for P pack
// (v_cvt_pk_bf16_f32). Numerics: 3-term Markidis hi/lo; hi+lo self-corrects
// under any hi rounding mode, so output matches r2/r4 at ~2^-17.

#define SB 4096
#define DDIM 64

typedef __attribute__((ext_vector_type(16))) float f32x16;
typedef __attribute__((ext_vector_type(8)))  float f32x8;
typedef __attribute__((ext_vector_type(4)))  float f32x4;
typedef __attribute__((ext_vector_type(8)))  short bf16x8;

static __device__ __forceinline__ unsigned short bf16_rne(float f) {
  union { float f; uint32_t u; } v; v.f = f;
  uint32_t u = v.u + 0x7FFFu + ((v.u >> 16) & 1u);
  return (unsigned short)(u >> 16);
}
static __device__ __forceinline__ float bf16_tof(unsigned short h) {
  union { uint32_t u; float f; } v; v.u = ((uint32_t)h) << 16;
  return v.f;
}
static __device__ __forceinline__ f32x16 MFMA(bf16x8 a, bf16x8 b, f32x16 c) {
  return __builtin_amdgcn_mfma_f32_32x32x16_bf16(a, b, c, 0, 0, 0);
}

// ---- workspace layout ----
#define KF_BYTES  (4u << 20)
#define VT_BYTES  (2u << 20)
#define WS_NEEDED (8u << 20)

__device__ __constant__ int g_koff[16] = {0,1,2,3, 8,9,10,11, 4,5,6,7, 12,13,14,15};

// ================= precompute kernel (unchanged, verified r2-r4) =================
__global__ __launch_bounds__(256)
void precompute_kernel(const float* __restrict__ x, char* __restrict__ ws) {
  const int bid = blockIdx.x;
  const int tid = threadIdx.x;
  char* __restrict__ kfmt = ws;
  char* __restrict__ vthi = ws + KF_BYTES;
  char* __restrict__ vtlo = ws + KF_BYTES + VT_BYTES;
  if (bid < 512) {
    const int t   = bid * 256 + tid;
    const int row = t >> 3;
    const int seg = t & 7;
    f32x8 v = *(const f32x8*)(x + (size_t)row * 64 + seg * 8);
    bf16x8 h, l;
#pragma unroll
    for (int j = 0; j < 8; ++j) {
      unsigned short hi = bf16_rne(v[j]);
      h[j] = (short)hi;
      l[j] = (short)bf16_rne(v[j] - bf16_tof(hi));
    }
    char* dst = kfmt + (size_t)row * 256 + seg * 16;
    *(bf16x8*)dst         = h;
    *(bf16x8*)(dst + 128) = l;
  } else {
    const int w = (bid - 512) * 4 + (tid >> 6);
    const int b = w >> 8;
    const int c = w & 255;
    const int d = tid & 63;
    unsigned short hs[16], ls[16];
#pragma unroll
    for (int s = 0; s < 16; ++s) {
      const int k = c * 16 + g_koff[s];
      float v = x[((size_t)(b * SB + k)) * 64 + d];
      hs[s] = bf16_rne(v);
      ls[s] = bf16_rne(v - bf16_tof(hs[s]));
    }
    bf16x8 h0, h1, l0, l1;
#pragma unroll
    for (int j = 0; j < 8; ++j) {
      h0[j] = (short)hs[j];     h1[j] = (short)hs[j + 8];
      l0[j] = (short)ls[j];     l1[j] = (short)ls[j + 8];
    }
    char* dh = vthi + (size_t)(b * 64 + d) * 8192 + c * 32;
    char* dl = vtlo + (size_t)(b * 64 + d) * 8192 + c * 32;
    *(bf16x8*)dh = h0; *(bf16x8*)(dh + 16) = h1;
    *(bf16x8*)dl = l0; *(bf16x8*)(dl + 16) = l1;
  }
}

// ================= main kernel =================
__global__ __launch_bounds__(512, 4)
void sdpa_main(const float* __restrict__ x, const char* __restrict__ ws,
               float* __restrict__ out) {
  __shared__ __align__(16) char smem[40960];   // 4 regions x 64 lanes x 160 B
  const int tid  = threadIdx.x;
  const int wv   = tid >> 6;
  const int lane = tid & 63;
  const int l31  = lane & 31;
  const int h5   = lane >> 5;

  // XCD swizzle (bijective over 512): b=(p>>1)&3, 2 XCDs/batch -> L2-fit K/V.
  const int p  = blockIdx.x;
  const int b  = (p >> 1) & 3;
  const int qt = ((p & 1) << 6) | (p >> 3);   // 0..127
  const int q0 = qt * 32;

  const float* __restrict__ xb = x + (size_t)b * (SB * DDIM);
  const char* __restrict__ kfmt = ws;
  const char* __restrict__ vthi = ws + KF_BYTES;
  const char* __restrict__ vtlo = ws + KF_BYTES + VT_BYTES;

  const float NEG = -3.0e38f;

  // ---- Q fragments (rows q0+l31), scale 0.125, hi/lo split ----
  bf16x8 qh[4], ql[4];
#pragma unroll
  for (int dc = 0; dc < 4; ++dc) {
    const float* ptr = xb + (size_t)(q0 + l31) * DDIM + dc * 16 + h5 * 8;
    f32x4 a = *(const f32x4*)ptr;
    f32x4 c = *(const f32x4*)(ptr + 4);
    float v[8] = {a[0], a[1], a[2], a[3], c[0], c[1], c[2], c[3]};
#pragma unroll
    for (int j = 0; j < 8; ++j) {
      float sv = v[j] * 0.125f;
      unsigned short hi = bf16_rne(sv);
      qh[dc][j] = (short)hi;
      ql[dc][j] = (short)bf16_rne(sv - bf16_tof(hi));
    }
  }

  f32x16 ot0 = {}, ot1 = {};
  float mrun = NEG, lrun = 0.f;

  // wave-uniform base offsets -> force into SGPRs via readfirstlane
  const int kv0   = __builtin_amdgcn_readfirstlane(wv * 512);
  const int koffl = l31 * 256 + h5 * 16;        // per-lane (K)
  const int voffl = l31 * 8192 + h5 * 16;       // per-lane (V)
  const char* kstep = kfmt + (size_t)__builtin_amdgcn_readfirstlane((b * SB + kv0) * 256);
  const char* vhs   = vthi + (size_t)__builtin_amdgcn_readfirstlane(b * 64 * 8192 + kv0 * 2);
  const char* vls   = vtlo + (size_t)__builtin_amdgcn_readfirstlane(b * 64 * 8192 + kv0 * 2);

#pragma unroll 1
  for (int st = 0; st < 16; ++st) {
    // ---- K fragments (hi+lo) for this step ----
    bf16x8 kh[4], kl[4];
#pragma unroll
    for (int dc = 0; dc < 4; ++dc) {
      kh[dc] = *(const bf16x8*)(kstep + koffl + dc * 32);
      kl[dc] = *(const bf16x8*)(kstep + koffl + 128 + dc * 32);
    }

    // ---- QK^T: 12 MFMAs chained on a single accumulator (C-forwarding) ----
    f32x16 s = {};
    __builtin_amdgcn_s_setprio(1);
#pragma unroll
    for (int dc = 0; dc < 4; ++dc) s = MFMA(kh[dc], qh[dc], s);
#pragma unroll
    for (int dc = 0; dc < 4; ++dc) s = MFMA(kh[dc], ql[dc], s);
#pragma unroll
    for (int dc = 0; dc < 4; ++dc) s = MFMA(kl[dc], qh[dc], s);
    __builtin_amdgcn_s_setprio(0);

    // ---- issue V-hi (both d-halves) + V-lo (half 0); hidden under softmax ----
    bf16x8 vh[2][2], vl0[2];
#pragma unroll
    for (int df = 0; df < 2; ++df)
#pragma unroll
      for (int c = 0; c < 2; ++c)
        vh[df][c] = *(const bf16x8*)(vhs + (size_t)df * (32 * 8192) + voffl + c * 32);
#pragma unroll
    for (int c = 0; c < 2; ++c)
      vl0[c] = *(const bf16x8*)(vls + voffl + c * 32);

    // ---- online softmax (lane owns q-row l31 across its 32-k slice) ----
    float m0 = fmaxf(s[0], s[1]),   m1 = fmaxf(s[2], s[3]);
    float m2 = fmaxf(s[4], s[5]),   m3 = fmaxf(s[6], s[7]);
    float m4 = fmaxf(s[8], s[9]),   m5 = fmaxf(s[10], s[11]);
    float m6 = fmaxf(s[12], s[13]), m7 = fmaxf(s[14], s[15]);
    float a0 = fmaxf(m0, m1), a1 = fmaxf(m2, m3);
    float a2 = fmaxf(m4, m5), a3 = fmaxf(m6, m7);
    float pm = fmaxf(fmaxf(a0, a1), fmaxf(a2, a3));
    pm = fmaxf(pm, __shfl_xor(pm, 32));

    if (!__all(pm <= mrun)) {               // skip is exact: corr would be 1
      const float mnew = fmaxf(mrun, pm);
      const float corr = __expf(mrun - mnew);
      mrun = mnew;
      lrun *= corr;
#pragma unroll
      for (int r = 0; r < 16; ++r) { ot0[r] *= corr; ot1[r] *= corr; }
    }

    float pexp[16];
#pragma unroll
    for (int r = 0; r < 16; ++r) pexp[r] = __expf(s[r] - mrun);
    {
      float t0 = (pexp[0] + pexp[1]) + (pexp[2] + pexp[3]);
      float t1 = (pexp[4] + pexp[5]) + (pexp[6] + pexp[7]);
      float t2 = (pexp[8] + pexp[9]) + (pexp[10] + pexp[11]);
      float t3 = (pexp[12] + pexp[13]) + (pexp[14] + pexp[15]);
      lrun += (t0 + t1) + (t2 + t3);
    }

    // ---- pack P hi/lo via native bf16 casts (v_cvt_pk_bf16_f32) ----
    bf16x8 ph[2], pl[2];
#pragma unroll
    for (int c = 0; c < 2; ++c)
#pragma unroll
      for (int j = 0; j < 8; ++j) {
        float pv = pexp[c * 8 + j];
        __bf16 hb = (__bf16)pv;
        ph[c][j] = __builtin_bit_cast(short, hb);
        pl[c][j] = __builtin_bit_cast(short, (__bf16)(pv - (float)hb));
      }

    // ---- PV d-half 0 (issue V-lo half 1 first, hidden under these MFMAs) ----
    bf16x8 vl1[2];
#pragma unroll
    for (int c = 0; c < 2; ++c)
      vl1[c] = *(const bf16x8*)(vls + (size_t)(32 * 8192) + voffl + c * 32);

    __builtin_amdgcn_s_setprio(1);
#pragma unroll
    for (int c = 0; c < 2; ++c) {
      ot0 = MFMA(vh[0][c], ph[c], ot0);
      ot0 = MFMA(vh[0][c], pl[c], ot0);
      ot0 = MFMA(vl0[c],   ph[c], ot0);
    }
    // ---- PV d-half 1 ----
#pragma unroll
    for (int c = 0; c < 2; ++c) {
      ot1 = MFMA(vh[1][c], ph[c], ot1);
      ot1 = MFMA(vh[1][c], pl[c], ot1);
      ot1 = MFMA(vl1[c],   ph[c], ot1);
    }
    __builtin_amdgcn_s_setprio(0);

    kstep += 32 * 256;
    vhs   += 64;
    vls   += 64;
  }

  lrun += __shfl_xor(lrun, 32);

  // ---- 3-round tree merge of 8 kv-span partials in LDS ----
  auto writeR = [&](int r) {
    char* bse = smem + r * 10240 + lane * 160;
#pragma unroll
    for (int t = 0; t < 4; ++t) {
      f32x4 o = { ot0[t*4+0], ot0[t*4+1], ot0[t*4+2], ot0[t*4+3] };
      *(f32x4*)(bse + t * 16) = o;
    }
#pragma unroll
    for (int t = 0; t < 4; ++t) {
      f32x4 o = { ot1[t*4+0], ot1[t*4+1], ot1[t*4+2], ot1[t*4+3] };
      *(f32x4*)(bse + 64 + t * 16) = o;
    }
    f32x4 stv = { mrun, lrun, 0.f, 0.f };
    *(f32x4*)(bse + 128) = stv;
  };
  auto mergeR = [&](int r) {
    char* bse = smem + r * 10240 + lane * 160;
    f32x4 stv = *(f32x4*)(bse + 128);
    const float mw = stv[0], lw = stv[1];
    const float mn = fmaxf(mrun, mw);
    const float f0 = __expf(mrun - mn);
    const float f1 = __expf(mw - mn);
    mrun = mn;
    lrun = lrun * f0 + lw * f1;
#pragma unroll
    for (int t = 0; t < 4; ++t) {
      f32x4 o = *(f32x4*)(bse + t * 16);
#pragma unroll
      for (int e = 0; e < 4; ++e) ot0[t*4+e] = ot0[t*4+e] * f0 + o[e] * f1;
    }
#pragma unroll
    for (int t = 0; t < 4; ++t) {
      f32x4 o = *(f32x4*)(bse + 64 + t * 16);
#pragma unroll
      for (int e = 0; e < 4; ++e) ot1[t*4+e] = ot1[t*4+e] * f0 + o[e] * f1;
    }
  };

  __syncthreads();
  if (wv >= 4) writeR(wv - 4);
  __syncthreads();
  if (wv < 4) mergeR(wv);
  __syncthreads();
  if (wv == 2 || wv == 3) writeR(wv - 2);
  __syncthreads();
  if (wv < 2) mergeR(wv);
  __syncthreads();
  if (wv == 1) writeR(0);
  __syncthreads();
  if (wv == 0) {
    mergeR(0);
    const float inv = 1.0f / lrun;
    const size_t rowoff = ((size_t)b * SB + q0 + l31) * DDIM;
#pragma unroll
    for (int t = 0; t < 4; ++t) {
      const int dbase = t * 8 + h5 * 4;
      f32x4 o = { ot0[t*4+0] * inv, ot0[t*4+1] * inv,
                  ot0[t*4+2] * inv, ot0[t*4+3] * inv };
      *(f32x4*)(out + rowoff + dbase) = o;
    }
#pragma unroll
    for (int t = 0; t < 4; ++t) {
      const int dbase = 32 + t * 8 + h5 * 4;
      f32x4 o = { ot1[t*4+0] * inv, ot1[t*4+1] * inv,
                  ot1[t*4+2] * inv, ot1[t*4+3] * inv };
      *(f32x4*)(out + rowoff + dbase) = o;
    }
  }
}

// ================= fallback (verified round-1 kernel) =================
#define KSTRIDE 272
#define VSTRIDE 144
#define VOFF    8704
#define WREG    17920

__global__ __launch_bounds__(512, 1)
void sdpa_fb(const float* __restrict__ x, float* __restrict__ out) {
  __shared__ __align__(16) char smem[143360];
  const int tid  = threadIdx.x;
  const int wv   = tid >> 6;
  const int lane = tid & 63;
  const int l31  = lane & 31;
  const int h5   = lane >> 5;
  const int bid  = blockIdx.x;
  const int b    = bid >> 6;
  const int q0   = (bid & 63) << 6;
  const float* __restrict__ xb = x + (size_t)b * (SB * DDIM);
  char* __restrict__ wl = smem + (size_t)wv * WREG;
  const float NEG = -3.0e38f;

  bf16x8 qh[2][4], ql[2][4];
#pragma unroll
  for (int qf = 0; qf < 2; ++qf)
#pragma unroll
    for (int dc = 0; dc < 4; ++dc) {
      const float* ptr = xb + (size_t)(q0 + qf * 32 + l31) * DDIM + dc * 16 + h5 * 8;
      f32x4 a = *(const f32x4*)ptr;
      f32x4 c = *(const f32x4*)(ptr + 4);
      float v[8] = {a[0], a[1], a[2], a[3], c[0], c[1], c[2], c[3]};
#pragma unroll
      for (int j = 0; j < 8; ++j) {
        float sv = v[j] * 0.125f;
        unsigned short hi = bf16_rne(sv);
        qh[qf][dc][j] = (short)hi;
        ql[qf][dc][j] = (short)bf16_rne(sv - bf16_tof(hi));
      }
    }

  f32x16 ot[2][2] = {};
  float mrun[2] = {NEG, NEG};
  float lrun[2] = {0.f, 0.f};
  const int kv0 = wv * (SB / 8);
  const int r0  = (lane >> 3) * 4;
  const int d0g = (lane & 7) * 8;
  const int vc  = r0 >> 4;
  const int vko = r0 & 15;
  const int vsA = ((vko >> 2) & 1) * 8 + ((vko >> 3) & 1) * 4;
  const uint32_t vcolb = (uint32_t)(vc * 16 + vsA) * 2;

#pragma unroll 1
  for (int st = 0; st < 16; ++st) {
    const int krow0 = kv0 + st * 32;
    bf16x8 hv[4], lv[4];
#pragma unroll
    for (int i = 0; i < 4; ++i) {
      f32x8 t = *(const f32x8*)(xb + (size_t)(krow0 + r0 + i) * DDIM + d0g);
#pragma unroll
      for (int j = 0; j < 8; ++j) {
        unsigned short hi = bf16_rne(t[j]);
        hv[i][j] = (short)hi;
        lv[i][j] = (short)bf16_rne(t[j] - bf16_tof(hi));
      }
      const int row = r0 + i;
      *(bf16x8*)(wl + row * KSTRIDE + d0g * 2)       = hv[i];
      *(bf16x8*)(wl + row * KSTRIDE + 128 + d0g * 2) = lv[i];
    }
#pragma unroll
    for (int dd = 0; dd < 8; ++dd) {
      const int d = d0g + dd;
      const uint32_t sw = ((uint32_t)((d >> 3) & 7)) << 4;
      char* rb = wl + VOFF + (uint32_t)d * VSTRIDE;
      short4 pa = make_short4(hv[0][dd], hv[1][dd], hv[2][dd], hv[3][dd]);
      short4 pb = make_short4(lv[0][dd], lv[1][dd], lv[2][dd], lv[3][dd]);
      *(short4*)(rb + (vcolb ^ sw))        = pa;
      *(short4*)(rb + ((64 + vcolb) ^ sw)) = pb;
    }

    bf16x8 kh[4], kl[4];
    {
      char* krow = wl + l31 * KSTRIDE;
#pragma unroll
      for (int dc = 0; dc < 4; ++dc) {
        const uint32_t off = (uint32_t)(dc * 32 + h5 * 16);
        kh[dc] = *(bf16x8*)(krow + off);
        kl[dc] = *(bf16x8*)(krow + 128 + off);
      }
    }
    f32x16 s0 = {}, s1 = {};
#pragma unroll
    for (int dc = 0; dc < 4; ++dc) {
      s0 = MFMA(kh[dc], qh[0][dc], s0);
      s1 = MFMA(kh[dc], qh[1][dc], s1);
      s0 = MFMA(kh[dc], ql[0][dc], s0);
      s1 = MFMA(kh[dc], ql[1][dc], s1);
      s0 = MFMA(kl[dc], qh[0][dc], s0);
      s1 = MFMA(kl[dc], qh[1][dc], s1);
    }

    bf16x8 ph[2][2], pl[2][2];
#pragma unroll
    for (int qf = 0; qf < 2; ++qf) {
      f32x16 sv = qf ? s1 : s0;
      float pm = sv[0];
#pragma unroll
      for (int r = 1; r < 16; ++r) pm = fmaxf(pm, sv[r]);
      pm = fmaxf(pm, __shfl_xor(pm, 32));
      const float mnew = fmaxf(mrun[qf], pm);
      const float corr = __expf(mrun[qf] - mnew);
      mrun[qf] = mnew;
      lrun[qf] *= corr;
#pragma unroll
      for (int df = 0; df < 2; ++df)
#pragma unroll
        for (int r = 0; r < 16; ++r) ot[qf][df][r] *= corr;
      float pv[16]; float ps = 0.f;
#pragma unroll
      for (int r = 0; r < 16; ++r) { pv[r] = __expf(sv[r] - mnew); ps += pv[r]; }
      lrun[qf] += ps;
#pragma unroll
      for (int c = 0; c < 2; ++c)
#pragma unroll
        for (int j = 0; j < 8; ++j) {
          float pvv = pv[c * 8 + j];
          unsigned short hi = bf16_rne(pvv);
          ph[qf][c][j] = (short)hi;
          pl[qf][c][j] = (short)bf16_rne(pvv - bf16_tof(hi));
        }
    }

#pragma unroll
    for (int df = 0; df < 2; ++df) {
      const int d = df * 32 + l31;
      char* rb = wl + VOFF + (uint32_t)d * VSTRIDE;
      const uint32_t sw = ((uint32_t)((d >> 3) & 7)) << 4;
      bf16x8 vh[2], vl2[2];
#pragma unroll
      for (int c = 0; c < 2; ++c) {
        const uint32_t off = (uint32_t)(c * 32 + h5 * 16);
        vh[c]  = *(bf16x8*)(rb + (off ^ sw));
        vl2[c] = *(bf16x8*)(rb + ((64 + off) ^ sw));
      }
#pragma unroll
      for (int qf = 0; qf < 2; ++qf)
#pragma unroll
        for (int c = 0; c < 2; ++c) {
          ot[qf][df] = MFMA(vh[c],  ph[qf][c], ot[qf][df]);
          ot[qf][df] = MFMA(vh[c],  pl[qf][c], ot[qf][df]);
          ot[qf][df] = MFMA(vl2[c], ph[qf][c], ot[qf][df]);
        }
    }
  }

#pragma unroll
  for (int qf = 0; qf < 2; ++qf) lrun[qf] += __shfl_xor(lrun[qf], 32);

  __syncthreads();
  if (wv > 0) {
    char* rbase = smem + (size_t)(wv - 1) * 17408 + (size_t)lane * 272;
#pragma unroll
    for (int qf = 0; qf < 2; ++qf)
#pragma unroll
      for (int df = 0; df < 2; ++df)
#pragma unroll
        for (int t = 0; t < 4; ++t) {
          f32x4 o = { ot[qf][df][t*4+0], ot[qf][df][t*4+1],
                      ot[qf][df][t*4+2], ot[qf][df][t*4+3] };
          *(f32x4*)(rbase + (qf * 128 + df * 64 + t * 16)) = o;
        }
    f32x4 stv = { mrun[0], lrun[0], mrun[1], lrun[1] };
    *(f32x4*)(rbase + 256) = stv;
  }
  __syncthreads();
  if (wv == 0) {
#pragma unroll 1
    for (int w = 1; w < 8; ++w) {
      char* rbase = smem + (size_t)(w - 1) * 17408 + (size_t)lane * 272;
      f32x4 stv = *(f32x4*)(rbase + 256);
#pragma unroll
      for (int qf = 0; qf < 2; ++qf) {
        const float mw = stv[qf * 2 + 0];
        const float lw = stv[qf * 2 + 1];
        const float mn = fmaxf(mrun[qf], mw);
        const float f0 = __expf(mrun[qf] - mn);
        const float f1 = __expf(mw - mn);
        mrun[qf] = mn;
        lrun[qf] = lrun[qf] * f0 + lw * f1;
#pragma unroll
        for (int df = 0; df < 2; ++df)
#pragma unroll
          for (int t = 0; t < 4; ++t) {
            f32x4 o = *(f32x4*)(rbase + (qf * 128 + df * 64 + t * 16));
#pragma unroll
            for (int e = 0; e < 4; ++e)
              ot[qf][df][t*4+e] = ot[qf][df][t*4+e] * f0 + o[e] * f1;
          }
      }
    }
#pragma unroll
    for (int qf = 0; qf < 2; ++qf) {
      const float inv = 1.0f / lrun[qf];
      const size_t rowoff = ((size_t)b * SB + q0 + qf * 32 + l31) * DDIM;
#pragma unroll
      for (int df = 0; df < 2; ++df)
#pragma unroll
        for (int t = 0; t < 4; ++t) {
          const int dbase = df * 32 + t * 8 + h5 * 4;
          f32x4 o = { ot[qf][df][t*4+0] * inv, ot[qf][df][t*4+1] * inv,
                      ot[qf][df][t*4+2] * inv, ot[qf][df][t*4+3] * inv };
          *(f32x4*)(out + rowoff + dbase) = o;
        }
    }
  }
}

extern "C" void kernel_launch(void* const* d_in, const int* in_sizes, int n_in,
                              void* d_out, int out_size, void* d_ws, size_t ws_size,
                              hipStream_t stream) {
  (void)in_sizes; (void)n_in; (void)out_size;
  const float* x = (const float*)d_in[0];
  float* o = (float*)d_out;
  if (ws_size >= (size_t)WS_NEEDED) {
    precompute_kernel<<<dim3(768), dim3(256), 0, stream>>>(x, (char*)d_ws);
    sdpa_main<<<dim3(512), dim3(512), 0, stream>>>(x, (const char*)d_ws, o);
  } else {
    sdpa_fb<<<dim3(256), dim3(512), 0, stream>>>(x, o);
  }
}

// Round 6
// 133.182 us; speedup vs baseline: 1.4122x; 1.4122x over previous
//
#include <hip/hip_runtime.h>
#include <cstdint>

// Self-attention (q=k=v=x), B=4, S=4096, D=64, fp32 in/out.
// Round 6: LDS-shared K/V staging + cross-block kv-split.
//  - precompute: bf16 hi/lo split of x into ws: kfmt [row][256B hi|lo] (4MB)
//    + vstep step-major V^T tiles [b][gstep][d][32 slots] hi|lo (4MB).
//  - main: 1024 blocks x 256 thr, __launch_bounds__(256,3): cap 170 regs,
//    3 blocks/CU = 12 waves/CU. Block = 4 q-tiles x 1 kv-eighth; per step
//    stage 16KB K+V tile to LDS dbuf via global_load_lds (pre-swizzled src,
//    swizzled ds_read), shared by 4 waves. Partials (m,l,raw acc) -> ws.
//  - merge: 8-way online-softmax combine, writes out.
// Numerics identical to passing r1-r5 (3-term Markidis, RNE split, __expf).

#define SB 4096
#define DDIM 64

typedef __attribute__((ext_vector_type(16))) float f32x16;
typedef __attribute__((ext_vector_type(8)))  float f32x8;
typedef __attribute__((ext_vector_type(4)))  float f32x4;
typedef __attribute__((ext_vector_type(8)))  short bf16x8;

static __device__ __forceinline__ unsigned short bf16_rne(float f) {
  union { float f; uint32_t u; } v; v.f = f;
  uint32_t u = v.u + 0x7FFFu + ((v.u >> 16) & 1u);
  return (unsigned short)(u >> 16);
}
static __device__ __forceinline__ float bf16_tof(unsigned short h) {
  union { uint32_t u; float f; } v; v.u = ((uint32_t)h) << 16;
  return v.f;
}
static __device__ __forceinline__ f32x16 MFMA(bf16x8 a, bf16x8 b, f32x16 c) {
  return __builtin_amdgcn_mfma_f32_32x32x16_bf16(a, b, c, 0, 0, 0);
}
static __device__ __forceinline__ void gl16(const char* src, char* ldsdst) {
  __builtin_amdgcn_global_load_lds(
      (const __attribute__((address_space(1))) unsigned int*)src,
      (__attribute__((address_space(3))) unsigned int*)ldsdst, 16, 0, 0);
}

// ---- workspace layout ----
#define KF_BYTES  (4u << 20)
#define VS_BYTES  (4u << 20)
#define PART_OFF  (8u << 20)
#define PART_STRIDE 8448u            // 128 m + 128 l + 8192 O (raw acc)
#define WS_NEEDED 42991616u          // 8 MiB + 512*8*8448

__device__ __constant__ int g_koff[16] = {0,1,2,3, 8,9,10,11, 4,5,6,7, 12,13,14,15};

// ================= precompute =================
__global__ __launch_bounds__(256)
void precompute_kernel(const float* __restrict__ x, char* __restrict__ ws) {
  const int bid = blockIdx.x;
  const int tid = threadIdx.x;
  if (bid < 512) {
    // kfmt: [b*4096+row]*256B : 64 hi bf16 | 64 lo bf16 (straight layout;
    // the main kernel's gload src applies the K XOR swizzle).
    const int t   = bid * 256 + tid;
    const int row = t >> 3;
    const int seg = t & 7;
    f32x8 v = *(const f32x8*)(x + (size_t)row * 64 + seg * 8);
    bf16x8 h, l;
#pragma unroll
    for (int j = 0; j < 8; ++j) {
      unsigned short hi = bf16_rne(v[j]);
      h[j] = (short)hi;
      l[j] = (short)bf16_rne(v[j] - bf16_tof(hi));
    }
    char* dst = ws + (size_t)row * 256 + seg * 16;
    *(bf16x8*)dst         = h;
    *(bf16x8*)(dst + 128) = l;
  } else {
    // vstep: tile per (b,gstep): [d 0..63][slot 0..31] hi (4KB) | lo (4KB)
    const int w = (bid - 512) * 4 + (tid >> 6);   // 0..511 = b*128+gstep
    const int b = w >> 7;
    const int gstep = w & 127;
    const int d = tid & 63;
    unsigned short hs[32], ls[32];
#pragma unroll
    for (int s = 0; s < 32; ++s) {
      const int k = gstep * 32 + (s & 16) + g_koff[s & 15];
      float v = x[((size_t)(b * SB + k)) * 64 + d];
      hs[s] = bf16_rne(v);
      ls[s] = bf16_rne(v - bf16_tof(hs[s]));
    }
    char* dst = ws + KF_BYTES + (size_t)w * 8192 + d * 64;
#pragma unroll
    for (int g = 0; g < 4; ++g) {
      bf16x8 h, l;
#pragma unroll
      for (int j = 0; j < 8; ++j) { h[j] = (short)hs[g*8+j]; l[j] = (short)ls[g*8+j]; }
      *(bf16x8*)(dst + g * 16)        = h;
      *(bf16x8*)(dst + 4096 + g * 16) = l;
    }
  }
}

// ================= main kernel =================
__global__ __launch_bounds__(256, 3)
void sdpa_main(const float* __restrict__ x, char* __restrict__ ws) {
  __shared__ __align__(16) char lds[32768];     // 2 x 16KB (K 8K | V 8K)
  const int tid  = threadIdx.x;
  const int wv   = tid >> 6;
  const int lane = tid & 63;
  const int l31  = lane & 31;
  const int h5   = lane >> 5;

  // bijective XCD decode: xcd=p&7 -> batch=xcd>>1; per-XCD set = 2MB (L2-fit)
  const int p    = blockIdx.x;
  const int xcd  = p & 7;
  const int b    = xcd >> 1;
  const int task = (p >> 3) * 2 + (xcd & 1);    // 0..255
  const int e    = task & 7;                     // kv-eighth
  const int g    = task >> 3;                    // q-group 0..31 (128 q)
  const int qt   = (b * 32 + g) * 4 + wv;        // global 32-q tile id

  const float* __restrict__ xb = x + (size_t)b * (SB * DDIM);

  // ---- Q fragments (rows g*128 + wv*32 + l31), scale 0.125, hi/lo ----
  bf16x8 qh[4], ql[4];
#pragma unroll
  for (int dc = 0; dc < 4; ++dc) {
    const float* ptr = xb + (size_t)(g * 128 + wv * 32 + l31) * DDIM + dc * 16 + h5 * 8;
    f32x4 a = *(const f32x4*)ptr;
    f32x4 c = *(const f32x4*)(ptr + 4);
    float v[8] = {a[0], a[1], a[2], a[3], c[0], c[1], c[2], c[3]};
#pragma unroll
    for (int j = 0; j < 8; ++j) {
      float sv = v[j] * 0.125f;
      unsigned short hi = bf16_rne(sv);
      qh[dc][j] = (short)hi;
      ql[dc][j] = (short)bf16_rne(sv - bf16_tof(hi));
    }
  }

  f32x16 ot0 = {}, ot1 = {};
  float mrun = -3.0e38f, lrun = 0.f;

  // staging role: waves 0-1 stage K (8KB), waves 2-3 stage V (8KB)
  const char* kst = ws + (size_t)(b * SB + e * 512) * 256;
  const char* vst = ws + KF_BYTES + (size_t)(b * 128 + e * 16) * 8192;
  const bool isK = (wv < 2);
  const int  j0  = wv * 4;
  uint32_t soff[4];
#pragma unroll
  for (int j = 0; j < 4; ++j) {
    uint32_t L = (uint32_t)(j0 + j) * 1024 + (uint32_t)lane * 16;
    if (j0 + j < 8) soff[j] = L ^ (((L >> 8) & 15u) << 4);
    else { uint32_t vL = L - 8192; uint32_t d = (vL & 4095) >> 6;
           soff[j] = vL ^ ((d & 3u) << 4); }
  }
  const char* sbase = isK ? kst : vst;

  // fragment-read swizzles
  const uint32_t swzk = (uint32_t)(l31 & 15) << 4;
  const uint32_t swzv = (uint32_t)(l31 & 3) << 4;
  const uint32_t krow = (uint32_t)l31 * 256;

  // prologue: stage step 0 into buf0
  {
    char* dbase = lds + (uint32_t)j0 * 1024;
#pragma unroll
    for (int j = 0; j < 4; ++j) gl16(sbase + soff[j], dbase + j * 1024);
    sbase += 8192;
  }
  __syncthreads();

#pragma unroll 1
  for (int st = 0; st < 16; ++st) {
    const int cur = st & 1;
    char* bc = lds + cur * 16384;

    // stage next tile into the other buffer
    if (st < 15) {
      char* dbase = lds + (cur ^ 1) * 16384 + (uint32_t)j0 * 1024;
#pragma unroll
      for (int j = 0; j < 4; ++j) gl16(sbase + soff[j], dbase + j * 1024);
      sbase += 8192;
    }

    // ---- K fragments from shared LDS ----
    bf16x8 kh[4], kl[4];
#pragma unroll
    for (int dc = 0; dc < 4; ++dc) {
      kh[dc] = *(const bf16x8*)(bc + krow + (((uint32_t)(dc * 32 + h5 * 16)) ^ swzk));
      kl[dc] = *(const bf16x8*)(bc + krow + (((uint32_t)(128 + dc * 32 + h5 * 16)) ^ swzk));
    }

    // ---- QK^T: two chains ----
    f32x16 sa = {}, sb = {};
    __builtin_amdgcn_s_setprio(1);
#pragma unroll
    for (int dc = 0; dc < 4; ++dc) { sa = MFMA(kh[dc], qh[dc], sa); sb = MFMA(kh[dc], ql[dc], sb); }
#pragma unroll
    for (int dc = 0; dc < 4; ++dc) sb = MFMA(kl[dc], qh[dc], sb);
    __builtin_amdgcn_s_setprio(0);

    // ---- V fragments (issued before softmax to hide LDS latency) ----
    bf16x8 vh[2][2], vl[2][2];
#pragma unroll
    for (int df = 0; df < 2; ++df) {
      const uint32_t drow = (uint32_t)(l31 + 32 * df) * 64;
#pragma unroll
      for (int c = 0; c < 2; ++c) {
        const uint32_t o = ((uint32_t)(c * 32 + h5 * 16)) ^ swzv;
        vh[df][c] = *(const bf16x8*)(bc + 8192 + drow + o);
        vl[df][c] = *(const bf16x8*)(bc + 8192 + 4096 + drow + o);
      }
    }

    float s[16];
#pragma unroll
    for (int r = 0; r < 16; ++r) s[r] = sa[r] + sb[r];

    // ---- online softmax (lane owns q-row l31) ----
    float m0 = fmaxf(s[0], s[1]),   m1 = fmaxf(s[2], s[3]);
    float m2 = fmaxf(s[4], s[5]),   m3 = fmaxf(s[6], s[7]);
    float m4 = fmaxf(s[8], s[9]),   m5 = fmaxf(s[10], s[11]);
    float m6 = fmaxf(s[12], s[13]), m7 = fmaxf(s[14], s[15]);
    float a0 = fmaxf(m0, m1), a1 = fmaxf(m2, m3);
    float a2 = fmaxf(m4, m5), a3 = fmaxf(m6, m7);
    float pm = fmaxf(fmaxf(a0, a1), fmaxf(a2, a3));
    pm = fmaxf(pm, __shfl_xor(pm, 32));

    if (!__all(pm <= mrun)) {                    // exact skip (corr==1)
      const float mnew = fmaxf(mrun, pm);
      const float corr = __expf(mrun - mnew);
      mrun = mnew;
      lrun *= corr;
#pragma unroll
      for (int r = 0; r < 16; ++r) { ot0[r] *= corr; ot1[r] *= corr; }
    }

#pragma unroll
    for (int r = 0; r < 16; ++r) s[r] = __expf(s[r] - mrun);
    {
      float t0 = (s[0] + s[1]) + (s[2] + s[3]);
      float t1 = (s[4] + s[5]) + (s[6] + s[7]);
      float t2 = (s[8] + s[9]) + (s[10] + s[11]);
      float t3 = (s[12] + s[13]) + (s[14] + s[15]);
      lrun += (t0 + t1) + (t2 + t3);
    }

    bf16x8 ph[2], pl[2];
#pragma unroll
    for (int c = 0; c < 2; ++c)
#pragma unroll
      for (int j = 0; j < 8; ++j) {
        float pv = s[c * 8 + j];
        unsigned short hi = bf16_rne(pv);
        ph[c][j] = (short)hi;
        pl[c][j] = (short)bf16_rne(pv - bf16_tof(hi));
      }

    // ---- PV ----
    __builtin_amdgcn_s_setprio(1);
#pragma unroll
    for (int c = 0; c < 2; ++c) {
      ot0 = MFMA(vh[0][c], ph[c], ot0);
      ot1 = MFMA(vh[1][c], ph[c], ot1);
      ot0 = MFMA(vh[0][c], pl[c], ot0);
      ot1 = MFMA(vh[1][c], pl[c], ot1);
    }
#pragma unroll
    for (int c = 0; c < 2; ++c) {
      ot0 = MFMA(vl[0][c], ph[c], ot0);
      ot1 = MFMA(vl[1][c], ph[c], ot1);
    }
    __builtin_amdgcn_s_setprio(0);

    __syncthreads();   // drains stage loads (vmcnt) + tile reads; flip buffers
  }

  lrun += __shfl_xor(lrun, 32);

  // ---- write partial (m, l, raw acc) to ws ----
  char* P = ws + PART_OFF + ((size_t)qt * 8 + e) * PART_STRIDE;
  if (h5 == 0) {
    *(float*)(P + l31 * 4)       = mrun;
    *(float*)(P + 128 + l31 * 4) = lrun;
  }
#pragma unroll
  for (int t = 0; t < 4; ++t) {
    f32x4 o = { ot0[t*4+0], ot0[t*4+1], ot0[t*4+2], ot0[t*4+3] };
    *(f32x4*)(P + 256 + (size_t)t * 1024 + lane * 16) = o;
  }
#pragma unroll
  for (int t = 0; t < 4; ++t) {
    f32x4 o = { ot1[t*4+0], ot1[t*4+1], ot1[t*4+2], ot1[t*4+3] };
    *(f32x4*)(P + 256 + (size_t)(4 + t) * 1024 + lane * 16) = o;
  }
}

// ================= merge kernel =================
__global__ __launch_bounds__(128)
void merge_kernel(const char* __restrict__ ws, float* __restrict__ out) {
  const int tid  = threadIdx.x;
  const int lane = tid & 63;
  const int l31  = lane & 31;
  const int h5   = lane >> 5;
  const int qt   = blockIdx.x * 2 + (tid >> 6);   // 0..511
  const char* base = ws + PART_OFF + (size_t)qt * 8 * PART_STRIDE;

  float m[8], l[8];
#pragma unroll
  for (int e = 0; e < 8; ++e) {
    const char* P = base + (size_t)e * PART_STRIDE;
    m[e] = *(const float*)(P + l31 * 4);
    l[e] = *(const float*)(P + 128 + l31 * 4);
  }
  float M = m[0];
#pragma unroll
  for (int e = 1; e < 8; ++e) M = fmaxf(M, m[e]);
  float w[8], L = 0.f;
#pragma unroll
  for (int e = 0; e < 8; ++e) { w[e] = __expf(m[e] - M); L += l[e] * w[e]; }
  const float invL = 1.0f / L;

  const int b   = qt >> 7;
  const int qin = (qt & 127) * 32 + l31;
  const size_t rowoff = ((size_t)b * SB + qin) * DDIM;

#pragma unroll
  for (int a = 0; a < 2; ++a)
#pragma unroll
    for (int t = 0; t < 4; ++t) {
      f32x4 acc = {0.f, 0.f, 0.f, 0.f};
#pragma unroll
      for (int e = 0; e < 8; ++e) {
        f32x4 v = *(const f32x4*)(base + (size_t)e * PART_STRIDE + 256 +
                                  (size_t)(a * 4 + t) * 1024 + lane * 16);
        acc += v * w[e];
      }
      const int d0 = a * 32 + t * 8 + h5 * 4;
      f32x4 o = { acc[0] * invL, acc[1] * invL, acc[2] * invL, acc[3] * invL };
      *(f32x4*)(out + rowoff + d0) = o;
    }
}

// ================= fallback (verified round-1 kernel) =================
#define KSTRIDE 272
#define VSTRIDE 144
#define VOFF    8704
#define WREG    17920

__global__ __launch_bounds__(512, 1)
void sdpa_fb(const float* __restrict__ x, float* __restrict__ out) {
  __shared__ __align__(16) char smem[143360];
  const int tid  = threadIdx.x;
  const int wv   = tid >> 6;
  const int lane = tid & 63;
  const int l31  = lane & 31;
  const int h5   = lane >> 5;
  const int bid  = blockIdx.x;
  const int b    = bid >> 6;
  const int q0   = (bid & 63) << 6;
  const float* __restrict__ xb = x + (size_t)b * (SB * DDIM);
  char* __restrict__ wl = smem + (size_t)wv * WREG;
  const float NEG = -3.0e38f;

  bf16x8 qh[2][4], ql[2][4];
#pragma unroll
  for (int qf = 0; qf < 2; ++qf)
#pragma unroll
    for (int dc = 0; dc < 4; ++dc) {
      const float* ptr = xb + (size_t)(q0 + qf * 32 + l31) * DDIM + dc * 16 + h5 * 8;
      f32x4 a = *(const f32x4*)ptr;
      f32x4 c = *(const f32x4*)(ptr + 4);
      float v[8] = {a[0], a[1], a[2], a[3], c[0], c[1], c[2], c[3]};
#pragma unroll
      for (int j = 0; j < 8; ++j) {
        float sv = v[j] * 0.125f;
        unsigned short hi = bf16_rne(sv);
        qh[qf][dc][j] = (short)hi;
        ql[qf][dc][j] = (short)bf16_rne(sv - bf16_tof(hi));
      }
    }

  f32x16 ot[2][2] = {};
  float mrun[2] = {NEG, NEG};
  float lrun[2] = {0.f, 0.f};
  const int kv0 = wv * (SB / 8);
  const int r0  = (lane >> 3) * 4;
  const int d0g = (lane & 7) * 8;
  const int vc  = r0 >> 4;
  const int vko = r0 & 15;
  const int vsA = ((vko >> 2) & 1) * 8 + ((vko >> 3) & 1) * 4;
  const uint32_t vcolb = (uint32_t)(vc * 16 + vsA) * 2;

#pragma unroll 1
  for (int st = 0; st < 16; ++st) {
    const int krow0 = kv0 + st * 32;
    bf16x8 hv[4], lv[4];
#pragma unroll
    for (int i = 0; i < 4; ++i) {
      f32x8 t = *(const f32x8*)(xb + (size_t)(krow0 + r0 + i) * DDIM + d0g);
#pragma unroll
      for (int j = 0; j < 8; ++j) {
        unsigned short hi = bf16_rne(t[j]);
        hv[i][j] = (short)hi;
        lv[i][j] = (short)bf16_rne(t[j] - bf16_tof(hi));
      }
      const int row = r0 + i;
      *(bf16x8*)(wl + row * KSTRIDE + d0g * 2)       = hv[i];
      *(bf16x8*)(wl + row * KSTRIDE + 128 + d0g * 2) = lv[i];
    }
#pragma unroll
    for (int dd = 0; dd < 8; ++dd) {
      const int d = d0g + dd;
      const uint32_t sw = ((uint32_t)((d >> 3) & 7)) << 4;
      char* rb = wl + VOFF + (uint32_t)d * VSTRIDE;
      short4 pa = make_short4(hv[0][dd], hv[1][dd], hv[2][dd], hv[3][dd]);
      short4 pb = make_short4(lv[0][dd], lv[1][dd], lv[2][dd], lv[3][dd]);
      *(short4*)(rb + (vcolb ^ sw))        = pa;
      *(short4*)(rb + ((64 + vcolb) ^ sw)) = pb;
    }

    bf16x8 kh[4], kl[4];
    {
      char* krow = wl + l31 * KSTRIDE;
#pragma unroll
      for (int dc = 0; dc < 4; ++dc) {
        const uint32_t off = (uint32_t)(dc * 32 + h5 * 16);
        kh[dc] = *(bf16x8*)(krow + off);
        kl[dc] = *(bf16x8*)(krow + 128 + off);
      }
    }
    f32x16 s0 = {}, s1 = {};
#pragma unroll
    for (int dc = 0; dc < 4; ++dc) {
      s0 = MFMA(kh[dc], qh[0][dc], s0);
      s1 = MFMA(kh[dc], qh[1][dc], s1);
      s0 = MFMA(kh[dc], ql[0][dc], s0);
      s1 = MFMA(kh[dc], ql[1][dc], s1);
      s0 = MFMA(kl[dc], qh[0][dc], s0);
      s1 = MFMA(kl[dc], qh[1][dc], s1);
    }

    bf16x8 ph[2][2], pl[2][2];
#pragma unroll
    for (int qf = 0; qf < 2; ++qf) {
      f32x16 sv = qf ? s1 : s0;
      float pm = sv[0];
#pragma unroll
      for (int r = 1; r < 16; ++r) pm = fmaxf(pm, sv[r]);
      pm = fmaxf(pm, __shfl_xor(pm, 32));
      const float mnew = fmaxf(mrun[qf], pm);
      const float corr = __expf(mrun[qf] - mnew);
      mrun[qf] = mnew;
      lrun[qf] *= corr;
#pragma unroll
      for (int df = 0; df < 2; ++df)
#pragma unroll
        for (int r = 0; r < 16; ++r) ot[qf][df][r] *= corr;
      float pv[16]; float ps = 0.f;
#pragma unroll
      for (int r = 0; r < 16; ++r) { pv[r] = __expf(sv[r] - mnew); ps += pv[r]; }
      lrun[qf] += ps;
#pragma unroll
      for (int c = 0; c < 2; ++c)
#pragma unroll
        for (int j = 0; j < 8; ++j) {
          float pvv = pv[c * 8 + j];
          unsigned short hi = bf16_rne(pvv);
          ph[qf][c][j] = (short)hi;
          pl[qf][c][j] = (short)bf16_rne(pvv - bf16_tof(hi));
        }
    }

#pragma unroll
    for (int df = 0; df < 2; ++df) {
      const int d = df * 32 + l31;
      char* rb = wl + VOFF + (uint32_t)d * VSTRIDE;
      const uint32_t sw = ((uint32_t)((d >> 3) & 7)) << 4;
      bf16x8 vh[2], vl2[2];
#pragma unroll
      for (int c = 0; c < 2; ++c) {
        const uint32_t off = (uint32_t)(c * 32 + h5 * 16);
        vh[c]  = *(bf16x8*)(rb + (off ^ sw));
        vl2[c] = *(bf16x8*)(rb + ((64 + off) ^ sw));
      }
#pragma unroll
      for (int qf = 0; qf < 2; ++qf)
#pragma unroll
        for (int c = 0; c < 2; ++c) {
          ot[qf][df] = MFMA(vh[c],  ph[qf][c], ot[qf][df]);
          ot[qf][df] = MFMA(vh[c],  pl[qf][c], ot[qf][df]);
          ot[qf][df] = MFMA(vl2[c], ph[qf][c], ot[qf][df]);
        }
    }
  }

#pragma unroll
  for (int qf = 0; qf < 2; ++qf) lrun[qf] += __shfl_xor(lrun[qf], 32);

  __syncthreads();
  if (wv > 0) {
    char* rbase = smem + (size_t)(wv - 1) * 17408 + (size_t)lane * 272;
#pragma unroll
    for (int qf = 0; qf < 2; ++qf)
#pragma unroll
      for (int df = 0; df < 2; ++df)
#pragma unroll
        for (int t = 0; t < 4; ++t) {
          f32x4 o = { ot[qf][df][t*4+0], ot[qf][df][t*4+1],
                      ot[qf][df][t*4+2], ot[qf][df][t*4+3] };
          *(f32x4*)(rbase + (qf * 128 + df * 64 + t * 16)) = o;
        }
    f32x4 stv = { mrun[0], lrun[0], mrun[1], lrun[1] };
    *(f32x4*)(rbase + 256) = stv;
  }
  __syncthreads();
  if (wv == 0) {
#pragma unroll 1
    for (int w = 1; w < 8; ++w) {
      char* rbase = smem + (size_t)(w - 1) * 17408 + (size_t)lane * 272;
      f32x4 stv = *(f32x4*)(rbase + 256);
#pragma unroll
      for (int qf = 0; qf < 2; ++qf) {
        const float mw = stv[qf * 2 + 0];
        const float lw = stv[qf * 2 + 1];
        const float mn = fmaxf(mrun[qf], mw);
        const float f0 = __expf(mrun[qf] - mn);
        const float f1 = __expf(mw - mn);
        mrun[qf] = mn;
        lrun[qf] = lrun[qf] * f0 + lw * f1;
#pragma unroll
        for (int df = 0; df < 2; ++df)
#pragma unroll
          for (int t = 0; t < 4; ++t) {
            f32x4 o = *(f32x4*)(rbase + (qf * 128 + df * 64 + t * 16));
#pragma unroll
            for (int eidx = 0; eidx < 4; ++eidx)
              ot[qf][df][t*4+eidx] = ot[qf][df][t*4+eidx] * f0 + o[eidx] * f1;
          }
      }
    }
#pragma unroll
    for (int qf = 0; qf < 2; ++qf) {
      const float inv = 1.0f / lrun[qf];
      const size_t rowoff = ((size_t)b * SB + q0 + qf * 32 + l31) * DDIM;
#pragma unroll
      for (int df = 0; df < 2; ++df)
#pragma unroll
        for (int t = 0; t < 4; ++t) {
          const int dbase = df * 32 + t * 8 + h5 * 4;
          f32x4 o = { ot[qf][df][t*4+0] * inv, ot[qf][df][t*4+1] * inv,
                      ot[qf][df][t*4+2] * inv, ot[qf][df][t*4+3] * inv };
          *(f32x4*)(out + rowoff + dbase) = o;
        }
    }
  }
}

extern "C" void kernel_launch(void* const* d_in, const int* in_sizes, int n_in,
                              void* d_out, int out_size, void* d_ws, size_t ws_size,
                              hipStream_t stream) {
  (void)in_sizes; (void)n_in; (void)out_size;
  const float* x = (const float*)d_in[0];
  float* o = (float*)d_out;
  if (ws_size >= (size_t)WS_NEEDED) {
    precompute_kernel<<<dim3(640), dim3(256), 0, stream>>>(x, (char*)d_ws);
    sdpa_main<<<dim3(1024), dim3(256), 0, stream>>>(x, (char*)d_ws);
    merge_kernel<<<dim3(256), dim3(128), 0, stream>>>((const char*)d_ws, o);
  } else {
    sdpa_fb<<<dim3(256), dim3(512), 0, stream>>>(x, o);
  }
}